// Round 6
// baseline (164.694 us; speedup 1.0000x reference)
//
#include <hip/hip_runtime.h>
#include <hip/hip_bf16.h>

typedef short v8s __attribute__((ext_vector_type(8)));
typedef float v4f __attribute__((ext_vector_type(4)));

#define KSPLIT 4

// ---- dual-dtype element access (f32m: 0 = bf16, 1 = f32) ----
static __device__ __forceinline__ float ldv(const void* p, size_t i, int f32m) {
    if (f32m) return ((const float*)p)[i];
    return __bfloat162float(((const __hip_bfloat16*)p)[i]);
}
static __device__ __forceinline__ void stv(void* p, size_t i, float v, int f32m) {
    if (f32m) ((float*)p)[i] = v;
    else ((__hip_bfloat16*)p)[i] = __float2bfloat16(v);
}
static __device__ __forceinline__ unsigned short f2bu(float x) {
    __hip_bfloat16 h = __float2bfloat16(x);
    return *(unsigned short*)&h;
}
static __device__ __forceinline__ float bu2f(unsigned short u) {
    return __uint_as_float(((unsigned)u) << 16);
}

// Robust scalar decode: handles int32, float32, or bf16-in-low-16 encodings.
static __device__ __forceinline__ float decode_scalar(const void* p) {
    unsigned u = *(const unsigned*)p;
    unsigned e32 = (u >> 23) & 0xff;
    if (e32 >= 97 && e32 <= 160) return __uint_as_float(u);
    unsigned lo = u & 0xffffu;
    unsigned e16 = (lo >> 7) & 0xff;
    if ((u >> 16) == 0 && e16 >= 97 && e16 <= 160)
        return __uint_as_float(lo << 16);
    return (float)(int)u;
}

// Per-block dtype sniff (deterministic; contains a barrier — call unconditionally).
static __device__ __forceinline__ int block_sniff(const void* feat) {
    const __hip_bfloat16* p = (const __hip_bfloat16*)feat;
    float v = __bfloat162float(p[threadIdx.x & 255]);
    int bad = !(fabsf(v) < 1e10f);
    return __syncthreads_or(bad) ? 1 : 0;
}

__device__ __forceinline__ float wave_sum(float v) {
    #pragma unroll
    for (int o = 32; o > 0; o >>= 1) v += __shfl_down(v, o, 64);
    return v;
}
__device__ __forceinline__ float wave_max(float v) {
    #pragma unroll
    for (int o = 32; o > 0; o >>= 1) v = fmaxf(v, __shfl_down(v, o, 64));
    return v;
}

// K1: prep (feat -> bf16 copy, 8 elems/thread) + block 0 extras:
//   - zero misc (loss accumulator + done counter)
//   - 256-thread counting sort of labels -> counts/offs/rows (CSR)
__global__ __launch_bounds__(256) void prep_sort(
        const void* __restrict__ feat, unsigned short* __restrict__ featb, int total,
        const int* __restrict__ labels, int* __restrict__ counts,
        int* __restrict__ offs, int* __restrict__ rows,
        float* __restrict__ misc, int Nn, int C) {
    int f32m = block_sniff(feat);
    int tid = threadIdx.x;
    int i = (blockIdx.x * 256 + tid) * 8;
    if (i < total) {
        if (f32m) {
            const float* f = (const float*)feat + i;
            unsigned short r[8];
            #pragma unroll
            for (int u = 0; u < 8; ++u) r[u] = f2bu(f[u]);
            *(v8s*)(featb + i) = *(v8s*)r;
        } else {
            *(v8s*)(featb + i) = *(const v8s*)((const unsigned short*)feat + i);
        }
    }
    if (blockIdx.x != 0) return;

    if (tid < 16) misc[tid] = 0.f;   // [0]=loss acc (f32), [1]=counter (int bits 0)

    __shared__ int h[1024];
    __shared__ int ex[256];
    __shared__ int cur[1024];
    #pragma unroll
    for (int u = 0; u < 4; ++u) h[tid + 256 * u] = 0;
    __syncthreads();
    for (int k = tid; k < Nn; k += 256) atomicAdd(&h[labels[k]], 1);
    __syncthreads();
    int b0 = h[4 * tid], b1 = h[4 * tid + 1], b2 = h[4 * tid + 2], b3 = h[4 * tid + 3];
    int s = b0 + b1 + b2 + b3;
    ex[tid] = s;
    __syncthreads();
    for (int d = 1; d < 256; d <<= 1) {
        int v = (tid >= d) ? ex[tid - d] : 0;
        __syncthreads();
        ex[tid] += v;
        __syncthreads();
    }
    int excl = ex[tid] - s;
    int o0 = excl, o1 = o0 + b0, o2 = o1 + b1, o3 = o2 + b2;
    counts[4 * tid] = b0; counts[4 * tid + 1] = b1;
    counts[4 * tid + 2] = b2; counts[4 * tid + 3] = b3;
    offs[4 * tid] = o0; offs[4 * tid + 1] = o1;
    offs[4 * tid + 2] = o2; offs[4 * tid + 3] = o3;
    cur[4 * tid] = o0; cur[4 * tid + 1] = o1;
    cur[4 * tid + 2] = o2; cur[4 * tid + 3] = o3;
    __syncthreads();
    for (int k = tid; k < Nn; k += 256) {
        int pos = atomicAdd(&cur[labels[k]], 1);
        rows[pos] = k;
    }
}

// K2: finalize stats. Block = (class c = blockIdx.y, 256-col chunk = blockIdx.x).
__global__ __launch_bounds__(256) void finalize_stats(
        const unsigned short* __restrict__ featb,
        const int* __restrict__ counts, const int* __restrict__ offs,
        const int* __restrict__ rows,
        const void* __restrict__ ave, const void* __restrict__ cov,
        const void* __restrict__ amount, const void* __restrict__ W,
        const void* __restrict__ feat,
        void* __restrict__ out, size_t off_ave, size_t off_cov, size_t off_amt,
        unsigned short* __restrict__ Wb, unsigned short* __restrict__ W2b,
        unsigned short* __restrict__ Cb, unsigned short* __restrict__ Gb,
        float* __restrict__ T3p, int A, int A8) {
    __shared__ float sb[4];
    int f32m = block_sniff(feat);
    int c = blockIdx.y;
    int a = blockIdx.x * 256 + threadIdx.x;
    size_t idx = (size_t)c * A + a;
    int cnti = counts[c];
    int start = offs[c];
    float s1 = 0.f, s2 = 0.f;
    for (int i = 0; i < cnti; ++i) {
        float x = bu2f(featb[(size_t)rows[start + i] * A + a]);
        s1 += x;
        s2 += x * x;
    }
    float cnt = (float)cnti;
    float denom = cnti > 0 ? cnt : 1.f;
    float mean = s1 / denom;
    float var = fmaxf((s2 - cnt * mean * mean) / denom, 0.f);
    float amt = ldv(amount, c, f32m);
    float tot = cnt + amt;
    float w = tot > 0.f ? (cnt / tot) : 0.f;   // nan_to_num(0/0) -> 0
    float av = ldv(ave, idx, f32m);
    float cv = ldv(cov, idx, f32m);
    float d = av - mean;
    float ncv = cv * (1.f - w) + var * w + w * (1.f - w) * d * d;
    float nav = av * (1.f - w) + mean * w;
    stv(out, off_cov + idx, ncv, f32m);
    stv(out, off_ave + idx, nav, f32m);
    float wv = ldv(W, idx, f32m);
    Wb[idx] = f2bu(wv);
    W2b[idx] = f2bu(wv * wv);
    Cb[idx] = f2bu(ncv);
    Gb[idx] = f2bu(ncv * wv);
    if (a == 0) stv(out, off_amt + c, amt + cnt, f32m);
    float s = wave_sum(wv * wv * ncv);
    int lane = threadIdx.x & 63, wid = threadIdx.x >> 6;
    if (lane == 0) sb[wid] = s;
    __syncthreads();
    if (threadIdx.x == 0) T3p[(size_t)c * A8 + blockIdx.x] = sb[0] + sb[1] + sb[2] + sb[3];
}

// K3: split-K fused MFMA triple GEMM, LDS-free / barrier-free.
// mfma_f32_16x16x32_bf16 A/B fragment = 16 contiguous bytes at row (lane&15),
// k-chunk (lane>>4): loaded DIRECTLY from row-major global arrays.
// Wave = 16 rows x 64 cols; block = 4 waves (64x64); grid (Cpad/64, Nn/64, KSPLIT).
__global__ __launch_bounds__(256) void triple_gemm_mfma(
        const unsigned short* __restrict__ featb,
        const unsigned short* __restrict__ Wb,
        const unsigned short* __restrict__ W2b,
        const unsigned short* __restrict__ Cb,
        const unsigned short* __restrict__ Gb,
        const int* __restrict__ labels,
        float* __restrict__ partY, float* __restrict__ partT1, float* __restrict__ partT2,
        int Cpad, int A, size_t NC) {
    int tid = threadIdx.x, wv = tid >> 6, lane = tid & 63;
    int n0 = blockIdx.y * 64, j0 = blockIdx.x * 64;
    int kslice = A / KSPLIT;
    int k0 = blockIdx.z * kslice;
    int r = lane & 15, q = lane >> 4;

    int nrow = n0 + wv * 16 + r;
    int lab = labels[nrow];
    const unsigned short* pF = featb + (size_t)nrow * A + k0 + q * 8;
    const unsigned short* pC = Cb + (size_t)lab * A + k0 + q * 8;
    const unsigned short* pG = Gb + (size_t)lab * A + k0 + q * 8;
    const unsigned short* pW0 = Wb  + (size_t)(j0 + 0  + r) * A + k0 + q * 8;
    const unsigned short* pW1 = Wb  + (size_t)(j0 + 16 + r) * A + k0 + q * 8;
    const unsigned short* pW2 = Wb  + (size_t)(j0 + 32 + r) * A + k0 + q * 8;
    const unsigned short* pW3 = Wb  + (size_t)(j0 + 48 + r) * A + k0 + q * 8;
    const unsigned short* pQ0 = W2b + (size_t)(j0 + 0  + r) * A + k0 + q * 8;
    const unsigned short* pQ1 = W2b + (size_t)(j0 + 16 + r) * A + k0 + q * 8;
    const unsigned short* pQ2 = W2b + (size_t)(j0 + 32 + r) * A + k0 + q * 8;
    const unsigned short* pQ3 = W2b + (size_t)(j0 + 48 + r) * A + k0 + q * 8;

    v4f aY[4] = {{0,0,0,0},{0,0,0,0},{0,0,0,0},{0,0,0,0}};
    v4f aT1[4] = {{0,0,0,0},{0,0,0,0},{0,0,0,0},{0,0,0,0}};
    v4f aT2[4] = {{0,0,0,0},{0,0,0,0},{0,0,0,0},{0,0,0,0}};

    for (int kk = 0; kk < kslice; kk += 32) {
        v8s f = *(const v8s*)pF;
        v8s c = *(const v8s*)pC;
        v8s g = *(const v8s*)pG;
        v8s w0 = *(const v8s*)pW0, w1 = *(const v8s*)pW1;
        v8s w2 = *(const v8s*)pW2, w3 = *(const v8s*)pW3;
        v8s q0 = *(const v8s*)pQ0, q1 = *(const v8s*)pQ1;
        v8s q2 = *(const v8s*)pQ2, q3 = *(const v8s*)pQ3;
        pF += 32; pC += 32; pG += 32;
        pW0 += 32; pW1 += 32; pW2 += 32; pW3 += 32;
        pQ0 += 32; pQ1 += 32; pQ2 += 32; pQ3 += 32;

        aY[0]  = __builtin_amdgcn_mfma_f32_16x16x32_bf16(f, w0, aY[0],  0, 0, 0);
        aY[1]  = __builtin_amdgcn_mfma_f32_16x16x32_bf16(f, w1, aY[1],  0, 0, 0);
        aY[2]  = __builtin_amdgcn_mfma_f32_16x16x32_bf16(f, w2, aY[2],  0, 0, 0);
        aY[3]  = __builtin_amdgcn_mfma_f32_16x16x32_bf16(f, w3, aY[3],  0, 0, 0);
        aT1[0] = __builtin_amdgcn_mfma_f32_16x16x32_bf16(c, q0, aT1[0], 0, 0, 0);
        aT1[1] = __builtin_amdgcn_mfma_f32_16x16x32_bf16(c, q1, aT1[1], 0, 0, 0);
        aT1[2] = __builtin_amdgcn_mfma_f32_16x16x32_bf16(c, q2, aT1[2], 0, 0, 0);
        aT1[3] = __builtin_amdgcn_mfma_f32_16x16x32_bf16(c, q3, aT1[3], 0, 0, 0);
        aT2[0] = __builtin_amdgcn_mfma_f32_16x16x32_bf16(g, w0, aT2[0], 0, 0, 0);
        aT2[1] = __builtin_amdgcn_mfma_f32_16x16x32_bf16(g, w1, aT2[1], 0, 0, 0);
        aT2[2] = __builtin_amdgcn_mfma_f32_16x16x32_bf16(g, w2, aT2[2], 0, 0, 0);
        aT2[3] = __builtin_amdgcn_mfma_f32_16x16x32_bf16(g, w3, aT2[3], 0, 0, 0);
    }

    // C/D layout: col = lane&15, row = (lane>>4)*4 + reg.
    float* pY = partY + (size_t)blockIdx.z * NC;
    float* p1 = partT1 + (size_t)blockIdx.z * NC;
    float* p2 = partT2 + (size_t)blockIdx.z * NC;
    int quad = lane >> 4, colb = lane & 15;
    #pragma unroll
    for (int t = 0; t < 4; ++t) {
        int j = j0 + t * 16 + colb;
        #pragma unroll
        for (int rr = 0; rr < 4; ++rr) {
            int n = n0 + wv * 16 + quad * 4 + rr;
            size_t idx = (size_t)n * Cpad + j;
            pY[idx] = aY[t][rr];
            p1[idx] = aT1[t][rr];
            p2[idx] = aT2[t][rr];
        }
    }
}

// K4: fused epilogue + row loss + final mean (atomic acc+counter in misc).
__global__ __launch_bounds__(256) void epilogue_rowloss(
        const float* __restrict__ partY, const float* __restrict__ partT1,
        const float* __restrict__ partT2, const float* __restrict__ T3p,
        const void* __restrict__ bias, const void* __restrict__ feat,
        const int* __restrict__ labels,
        void* __restrict__ out, size_t off_y,
        float* __restrict__ misc,
        int C, int Cpad, int A8, const void* ratio_p, size_t NC, int Nn) {
    __shared__ float sb[4];
    __shared__ float sM;
    __shared__ float sLabVal;
    int f32m = block_sniff(feat);
    int tid = threadIdx.x;
    int n = blockIdx.x;
    int lab = labels[n];
    float t3 = 0.f;
    for (int i = 0; i < A8; ++i) t3 += T3p[(size_t)lab * A8 + i];
    float ratio = decode_scalar(ratio_p);

    float vals[8];
    int nu = Cpad >> 8;
    float m = -3.4e38f;
    for (int u = 0; u < nu; ++u) {
        int j = u * 256 + tid;
        float v = -3.4e38f;
        if (j < C) {
            size_t idx = (size_t)n * Cpad + j;
            float y = 0.f, t1 = 0.f, t2 = 0.f;
            #pragma unroll
            for (int z = 0; z < KSPLIT; ++z) {
                y  += partY[z * NC + idx];
                t1 += partT1[z * NC + idx];
                t2 += partT2[z * NC + idx];
            }
            y += ldv(bias, j, f32m);
            stv(out, off_y + (size_t)n * C + j, y, f32m);
            v = y + 0.5f * ratio * (t1 - 2.f * t2 + t3);
            if (j == lab) sLabVal = v;
        }
        vals[u] = v;
        m = fmaxf(m, v);
    }
    m = wave_max(m);
    int lane = tid & 63, wid = tid >> 6;
    if (lane == 0) sb[wid] = m;
    __syncthreads();
    if (tid == 0) sM = fmaxf(fmaxf(sb[0], sb[1]), fmaxf(sb[2], sb[3]));
    __syncthreads();
    m = sM;
    float s = 0.f;
    for (int u = 0; u < nu; ++u) s += expf(vals[u] - m);   // -inf -> 0
    __syncthreads();
    s = wave_sum(s);
    if (lane == 0) sb[wid] = s;
    __syncthreads();
    if (tid == 0) {
        float rl = m + logf(sb[0] + sb[1] + sb[2] + sb[3]) - sLabVal;
        atomicAdd(&misc[0], rl);
        __threadfence();
        int old = atomicAdd((int*)&misc[1], 1);
        if (old == Nn - 1) {
            __threadfence();
            float tot = atomicAdd(&misc[0], 0.f);   // coherent read
            stv(out, 0, tot / (float)Nn, f32m);
        }
    }
}

extern "C" void kernel_launch(void* const* d_in, const int* in_sizes, int n_in,
                              void* d_out, int out_size, void* d_ws, size_t ws_size,
                              hipStream_t stream) {
    const void* feat   = d_in[0];
    const int*  labels = (const int*)d_in[1];
    const void* W      = d_in[2];
    const void* bias   = d_in[3];
    const void* ave    = d_in[4];
    const void* cov    = d_in[5];
    const void* amount = d_in[6];
    const void* ratiop = d_in[7];

    int NA = in_sizes[0];                  // N*A
    int Nn = in_sizes[1];                  // 512
    int C  = in_sizes[3];                  // 1000
    int A  = NA / Nn;                      // 2048
    int CA = in_sizes[2];                  // C*A
    int Cpad = ((C + 255) / 256) * 256;    // 1024
    int A8 = A / 256;                      // 8
    size_t NC = (size_t)Nn * Cpad;

    size_t off_y   = 1;
    size_t off_ave = off_y + (size_t)Nn * C;
    size_t off_cov = off_ave + (size_t)CA;
    size_t off_amt = off_cov + (size_t)CA;

    char* ws = (char*)d_ws;
    int*   w_cnt  = (int*)ws;                          // 1024
    int*   w_off  = w_cnt + 1024;                      // 1024
    int*   w_rows = w_off + 1024;                      // 1024
    float* w_misc = (float*)(w_rows + 1024);           // 16
    float* w_T3p  = w_misc + 16;                       // C*A8 (<= 8192)
    float* w_partY  = w_T3p + 8192;                    // KSPLIT*NC
    float* w_partT1 = w_partY + KSPLIT * NC;           // KSPLIT*NC
    float* w_partT2 = w_partT1 + KSPLIT * NC;          // KSPLIT*NC
    unsigned short* w_featb = (unsigned short*)(w_partT2 + KSPLIT * NC);  // NA
    unsigned short* w_Wb    = w_featb + NA;            // CA
    unsigned short* w_W2b   = w_Wb + CA;               // CA
    unsigned short* w_Cb    = w_W2b + CA;              // CA
    unsigned short* w_Gb    = w_Cb + CA;               // CA

    prep_sort<<<NA / 2048, 256, 0, stream>>>(feat, w_featb, NA, labels,
                                             w_cnt, w_off, w_rows, w_misc, Nn, C);
    dim3 g2(A8, C);
    finalize_stats<<<g2, 256, 0, stream>>>(w_featb, w_cnt, w_off, w_rows,
                                           ave, cov, amount, W, feat,
                                           d_out, off_ave, off_cov, off_amt,
                                           w_Wb, w_W2b, w_Cb, w_Gb, w_T3p, A, A8);
    dim3 g3(Cpad / 64, Nn / 64, KSPLIT);
    triple_gemm_mfma<<<g3, 256, 0, stream>>>(w_featb, w_Wb, w_W2b, w_Cb, w_Gb,
                                             labels, w_partY, w_partT1, w_partT2,
                                             Cpad, A, NC);
    epilogue_rowloss<<<Nn, 256, 0, stream>>>(w_partY, w_partT1, w_partT2, w_T3p,
                                             bias, feat, labels, d_out, off_y,
                                             w_misc, C, Cpad, A8, ratiop, NC, Nn);
}

// Round 7
// 146.670 us; speedup vs baseline: 1.1229x; 1.1229x over previous
//
#include <hip/hip_runtime.h>
#include <hip/hip_bf16.h>

typedef short v8s __attribute__((ext_vector_type(8)));
typedef float v4f __attribute__((ext_vector_type(4)));

#define KSPLIT 4

// ---- dual-dtype element access (f32m: 0 = bf16, 1 = f32) ----
static __device__ __forceinline__ float ldv(const void* p, size_t i, int f32m) {
    if (f32m) return ((const float*)p)[i];
    return __bfloat162float(((const __hip_bfloat16*)p)[i]);
}
static __device__ __forceinline__ void stv(void* p, size_t i, float v, int f32m) {
    if (f32m) ((float*)p)[i] = v;
    else ((__hip_bfloat16*)p)[i] = __float2bfloat16(v);
}
static __device__ __forceinline__ unsigned short f2bu(float x) {
    __hip_bfloat16 h = __float2bfloat16(x);
    return *(unsigned short*)&h;
}
static __device__ __forceinline__ float bu2f(unsigned short u) {
    return __uint_as_float(((unsigned)u) << 16);
}

// Robust scalar decode: handles int32, float32, or bf16-in-low-16 encodings.
static __device__ __forceinline__ float decode_scalar(const void* p) {
    unsigned u = *(const unsigned*)p;
    unsigned e32 = (u >> 23) & 0xff;
    if (e32 >= 97 && e32 <= 160) return __uint_as_float(u);
    unsigned lo = u & 0xffffu;
    unsigned e16 = (lo >> 7) & 0xff;
    if ((u >> 16) == 0 && e16 >= 97 && e16 <= 160)
        return __uint_as_float(lo << 16);
    return (float)(int)u;
}

// Per-block dtype sniff (deterministic; contains a barrier — call unconditionally).
static __device__ __forceinline__ int block_sniff(const void* feat) {
    const __hip_bfloat16* p = (const __hip_bfloat16*)feat;
    float v = __bfloat162float(p[threadIdx.x & 255]);
    int bad = !(fabsf(v) < 1e10f);
    return __syncthreads_or(bad) ? 1 : 0;
}

__device__ __forceinline__ float wave_sum(float v) {
    #pragma unroll
    for (int o = 32; o > 0; o >>= 1) v += __shfl_down(v, o, 64);
    return v;
}
__device__ __forceinline__ float wave_max(float v) {
    #pragma unroll
    for (int o = 32; o > 0; o >>= 1) v = fmaxf(v, __shfl_down(v, o, 64));
    return v;
}

// async global->LDS, 16B per lane, LDS dst = wave-uniform base + lane*16
static __device__ __forceinline__ void ld16(unsigned short* lds, const unsigned short* g) {
    __builtin_amdgcn_global_load_lds(
        (const __attribute__((address_space(1))) unsigned int*)g,
        (__attribute__((address_space(3))) unsigned int*)lds,
        16, 0, 0);
}

// K1: prep (feat -> bf16 copy, 8 elems/thread) + block 0 extras:
//   - zero misc (loss accumulator + done counter)
//   - 256-thread counting sort of labels -> counts/offs/rows (CSR)
__global__ __launch_bounds__(256) void prep_sort(
        const void* __restrict__ feat, unsigned short* __restrict__ featb, int total,
        const int* __restrict__ labels, int* __restrict__ counts,
        int* __restrict__ offs, int* __restrict__ rows,
        float* __restrict__ misc, int Nn, int C) {
    int f32m = block_sniff(feat);
    int tid = threadIdx.x;
    int i = (blockIdx.x * 256 + tid) * 8;
    if (i < total) {
        if (f32m) {
            const float* f = (const float*)feat + i;
            unsigned short r[8];
            #pragma unroll
            for (int u = 0; u < 8; ++u) r[u] = f2bu(f[u]);
            *(v8s*)(featb + i) = *(v8s*)r;
        } else {
            *(v8s*)(featb + i) = *(const v8s*)((const unsigned short*)feat + i);
        }
    }
    if (blockIdx.x != 0) return;

    if (tid < 16) misc[tid] = 0.f;   // [0]=loss acc (f32), [1]=counter (int bits 0)

    __shared__ int h[1024];
    __shared__ int ex[256];
    __shared__ int cur[1024];
    #pragma unroll
    for (int u = 0; u < 4; ++u) h[tid + 256 * u] = 0;
    __syncthreads();
    for (int k = tid; k < Nn; k += 256) atomicAdd(&h[labels[k]], 1);
    __syncthreads();
    int b0 = h[4 * tid], b1 = h[4 * tid + 1], b2 = h[4 * tid + 2], b3 = h[4 * tid + 3];
    int s = b0 + b1 + b2 + b3;
    ex[tid] = s;
    __syncthreads();
    for (int d = 1; d < 256; d <<= 1) {
        int v = (tid >= d) ? ex[tid - d] : 0;
        __syncthreads();
        ex[tid] += v;
        __syncthreads();
    }
    int excl = ex[tid] - s;
    int o0 = excl, o1 = o0 + b0, o2 = o1 + b1, o3 = o2 + b2;
    counts[4 * tid] = b0; counts[4 * tid + 1] = b1;
    counts[4 * tid + 2] = b2; counts[4 * tid + 3] = b3;
    offs[4 * tid] = o0; offs[4 * tid + 1] = o1;
    offs[4 * tid + 2] = o2; offs[4 * tid + 3] = o3;
    cur[4 * tid] = o0; cur[4 * tid + 1] = o1;
    cur[4 * tid + 2] = o2; cur[4 * tid + 3] = o3;
    __syncthreads();
    for (int k = tid; k < Nn; k += 256) {
        int pos = atomicAdd(&cur[labels[k]], 1);
        rows[pos] = k;
    }
}

// K2: finalize stats. Block = (class c = blockIdx.y, 256-col chunk = blockIdx.x).
__global__ __launch_bounds__(256) void finalize_stats(
        const unsigned short* __restrict__ featb,
        const int* __restrict__ counts, const int* __restrict__ offs,
        const int* __restrict__ rows,
        const void* __restrict__ ave, const void* __restrict__ cov,
        const void* __restrict__ amount, const void* __restrict__ W,
        const void* __restrict__ feat,
        void* __restrict__ out, size_t off_ave, size_t off_cov, size_t off_amt,
        unsigned short* __restrict__ Wb, unsigned short* __restrict__ W2b,
        unsigned short* __restrict__ Cb, unsigned short* __restrict__ Gb,
        float* __restrict__ T3p, int A, int A8) {
    __shared__ float sb[4];
    int f32m = block_sniff(feat);
    int c = blockIdx.y;
    int a = blockIdx.x * 256 + threadIdx.x;
    size_t idx = (size_t)c * A + a;
    int cnti = counts[c];
    int start = offs[c];
    float s1 = 0.f, s2 = 0.f;
    for (int i = 0; i < cnti; ++i) {
        float x = bu2f(featb[(size_t)rows[start + i] * A + a]);
        s1 += x;
        s2 += x * x;
    }
    float cnt = (float)cnti;
    float denom = cnti > 0 ? cnt : 1.f;
    float mean = s1 / denom;
    float var = fmaxf((s2 - cnt * mean * mean) / denom, 0.f);
    float amt = ldv(amount, c, f32m);
    float tot = cnt + amt;
    float w = tot > 0.f ? (cnt / tot) : 0.f;   // nan_to_num(0/0) -> 0
    float av = ldv(ave, idx, f32m);
    float cv = ldv(cov, idx, f32m);
    float d = av - mean;
    float ncv = cv * (1.f - w) + var * w + w * (1.f - w) * d * d;
    float nav = av * (1.f - w) + mean * w;
    stv(out, off_cov + idx, ncv, f32m);
    stv(out, off_ave + idx, nav, f32m);
    float wv = ldv(W, idx, f32m);
    Wb[idx] = f2bu(wv);
    W2b[idx] = f2bu(wv * wv);
    Cb[idx] = f2bu(ncv);
    Gb[idx] = f2bu(ncv * wv);
    if (a == 0) stv(out, off_amt + c, amt + cnt, f32m);
    float s = wave_sum(wv * wv * ncv);
    int lane = threadIdx.x & 63, wid = threadIdx.x >> 6;
    if (lane == 0) sb[wid] = s;
    __syncthreads();
    if (threadIdx.x == 0) T3p[(size_t)c * A8 + blockIdx.x] = sb[0] + sb[1] + sb[2] + sb[3];
}

// K3: split-K fused MFMA triple GEMM, LDS-staged via global_load_lds, BK=64.
// Wave w stages its 16-row A-slices (F,C,G) and 16-col B-slices (W,W2) in
// fragment order (lane-contiguous 16B), then all waves read all B-subtiles.
// 24 MFMAs per barrier-pair; 8 K-iters. Partials per split-K slice (no atomics).
__global__ __launch_bounds__(256) void triple_gemm_mfma(
        const unsigned short* __restrict__ featb,
        const unsigned short* __restrict__ Wb,
        const unsigned short* __restrict__ W2b,
        const unsigned short* __restrict__ Cb,
        const unsigned short* __restrict__ Gb,
        const int* __restrict__ labels,
        float* __restrict__ partY, float* __restrict__ partT1, float* __restrict__ partT2,
        int Cpad, int A, size_t NC) {
    __shared__ unsigned short sA[20480];   // F:0 C:4096 G:8192 W:12288 W2:16384
    __shared__ int sLab[64];
    int tid = threadIdx.x, wv = tid >> 6, lane = tid & 63;
    int n0 = blockIdx.y * 64, j0 = blockIdx.x * 64;
    int kslice = A / KSPLIT;
    int k0 = blockIdx.z * kslice;
    if (tid < 64) sLab[tid] = labels[n0 + tid];
    __syncthreads();

    int r = lane & 15, q = lane >> 4;
    int fr = wv * 16 + r;
    const unsigned short* pF = featb + (size_t)(n0 + fr) * A + k0 + q * 8;
    int lab = sLab[fr];
    const unsigned short* pC = Cb + (size_t)lab * A + k0 + q * 8;
    const unsigned short* pG = Gb + (size_t)lab * A + k0 + q * 8;
    const unsigned short* pW = Wb  + (size_t)(j0 + fr) * A + k0 + q * 8;
    const unsigned short* pQ = W2b + (size_t)(j0 + fr) * A + k0 + q * 8;
    unsigned short* dF = &sA[0     + wv * 1024];
    unsigned short* dC = &sA[4096  + wv * 1024];
    unsigned short* dG = &sA[8192  + wv * 1024];
    unsigned short* dW = &sA[12288 + wv * 1024];
    unsigned short* dQ = &sA[16384 + wv * 1024];

    v4f aY[4] = {{0,0,0,0},{0,0,0,0},{0,0,0,0},{0,0,0,0}};
    v4f aT1[4] = {{0,0,0,0},{0,0,0,0},{0,0,0,0},{0,0,0,0}};
    v4f aT2[4] = {{0,0,0,0},{0,0,0,0},{0,0,0,0},{0,0,0,0}};

    for (int kk = 0; kk < kslice; kk += 64) {
        ld16(dF, pF); ld16(dF + 512, pF + 32);
        ld16(dC, pC); ld16(dC + 512, pC + 32);
        ld16(dG, pG); ld16(dG + 512, pG + 32);
        ld16(dW, pW); ld16(dW + 512, pW + 32);
        ld16(dQ, pQ); ld16(dQ + 512, pQ + 32);
        pF += 64; pC += 64; pG += 64; pW += 64; pQ += 64;
        __syncthreads();   // drains LDS-DMA (vmcnt) + joins waves
        #pragma unroll
        for (int s = 0; s < 2; ++s) {
            v8s f = *(v8s*)&sA[0    + wv * 1024 + s * 512 + lane * 8];
            v8s c = *(v8s*)&sA[4096 + wv * 1024 + s * 512 + lane * 8];
            v8s g = *(v8s*)&sA[8192 + wv * 1024 + s * 512 + lane * 8];
            #pragma unroll
            for (int t = 0; t < 4; ++t) {
                v8s w  = *(v8s*)&sA[12288 + t * 1024 + s * 512 + lane * 8];
                v8s w2 = *(v8s*)&sA[16384 + t * 1024 + s * 512 + lane * 8];
                aY[t]  = __builtin_amdgcn_mfma_f32_16x16x32_bf16(f, w,  aY[t],  0, 0, 0);
                aT1[t] = __builtin_amdgcn_mfma_f32_16x16x32_bf16(c, w2, aT1[t], 0, 0, 0);
                aT2[t] = __builtin_amdgcn_mfma_f32_16x16x32_bf16(g, w,  aT2[t], 0, 0, 0);
            }
        }
        __syncthreads();
    }

    // C/D layout: col = lane&15, row = (lane>>4)*4 + reg.
    float* pY = partY + (size_t)blockIdx.z * NC;
    float* p1 = partT1 + (size_t)blockIdx.z * NC;
    float* p2 = partT2 + (size_t)blockIdx.z * NC;
    int quad = lane >> 4, colb = lane & 15;
    #pragma unroll
    for (int t = 0; t < 4; ++t) {
        int j = j0 + t * 16 + colb;
        #pragma unroll
        for (int rr = 0; rr < 4; ++rr) {
            int n = n0 + wv * 16 + quad * 4 + rr;
            size_t idx = (size_t)n * Cpad + j;
            pY[idx] = aY[t][rr];
            p1[idx] = aT1[t][rr];
            p2[idx] = aT2[t][rr];
        }
    }
}

// K4: fused epilogue + row loss + final mean (atomic acc+counter in misc).
__global__ __launch_bounds__(256) void epilogue_rowloss(
        const float* __restrict__ partY, const float* __restrict__ partT1,
        const float* __restrict__ partT2, const float* __restrict__ T3p,
        const void* __restrict__ bias, const void* __restrict__ feat,
        const int* __restrict__ labels,
        void* __restrict__ out, size_t off_y,
        float* __restrict__ misc,
        int C, int Cpad, int A8, const void* ratio_p, size_t NC, int Nn) {
    __shared__ float sb[4];
    __shared__ float sM;
    __shared__ float sLabVal;
    int f32m = block_sniff(feat);
    int tid = threadIdx.x;
    int n = blockIdx.x;
    int lab = labels[n];
    float t3 = 0.f;
    for (int i = 0; i < A8; ++i) t3 += T3p[(size_t)lab * A8 + i];
    float ratio = decode_scalar(ratio_p);

    float vals[8];
    int nu = Cpad >> 8;
    float m = -3.4e38f;
    for (int u = 0; u < nu; ++u) {
        int j = u * 256 + tid;
        float v = -3.4e38f;
        if (j < C) {
            size_t idx = (size_t)n * Cpad + j;
            float y = 0.f, t1 = 0.f, t2 = 0.f;
            #pragma unroll
            for (int z = 0; z < KSPLIT; ++z) {
                y  += partY[z * NC + idx];
                t1 += partT1[z * NC + idx];
                t2 += partT2[z * NC + idx];
            }
            y += ldv(bias, j, f32m);
            stv(out, off_y + (size_t)n * C + j, y, f32m);
            v = y + 0.5f * ratio * (t1 - 2.f * t2 + t3);
            if (j == lab) sLabVal = v;
        }
        vals[u] = v;
        m = fmaxf(m, v);
    }
    m = wave_max(m);
    int lane = tid & 63, wid = tid >> 6;
    if (lane == 0) sb[wid] = m;
    __syncthreads();
    if (tid == 0) sM = fmaxf(fmaxf(sb[0], sb[1]), fmaxf(sb[2], sb[3]));
    __syncthreads();
    m = sM;
    float s = 0.f;
    for (int u = 0; u < nu; ++u) s += expf(vals[u] - m);   // -inf -> 0
    __syncthreads();
    s = wave_sum(s);
    if (lane == 0) sb[wid] = s;
    __syncthreads();
    if (tid == 0) {
        float rl = m + logf(sb[0] + sb[1] + sb[2] + sb[3]) - sLabVal;
        atomicAdd(&misc[0], rl);
        __threadfence();
        int old = atomicAdd((int*)&misc[1], 1);
        if (old == Nn - 1) {
            __threadfence();
            float tot = atomicAdd(&misc[0], 0.f);   // coherent read
            stv(out, 0, tot / (float)Nn, f32m);
        }
    }
}

extern "C" void kernel_launch(void* const* d_in, const int* in_sizes, int n_in,
                              void* d_out, int out_size, void* d_ws, size_t ws_size,
                              hipStream_t stream) {
    const void* feat   = d_in[0];
    const int*  labels = (const int*)d_in[1];
    const void* W      = d_in[2];
    const void* bias   = d_in[3];
    const void* ave    = d_in[4];
    const void* cov    = d_in[5];
    const void* amount = d_in[6];
    const void* ratiop = d_in[7];

    int NA = in_sizes[0];                  // N*A
    int Nn = in_sizes[1];                  // 512
    int C  = in_sizes[3];                  // 1000
    int A  = NA / Nn;                      // 2048
    int CA = in_sizes[2];                  // C*A
    int Cpad = ((C + 255) / 256) * 256;    // 1024
    int A8 = A / 256;                      // 8
    size_t NC = (size_t)Nn * Cpad;

    size_t off_y   = 1;
    size_t off_ave = off_y + (size_t)Nn * C;
    size_t off_cov = off_ave + (size_t)CA;
    size_t off_amt = off_cov + (size_t)CA;

    char* ws = (char*)d_ws;
    int*   w_cnt  = (int*)ws;                          // 1024
    int*   w_off  = w_cnt + 1024;                      // 1024
    int*   w_rows = w_off + 1024;                      // 1024
    float* w_misc = (float*)(w_rows + 1024);           // 16
    float* w_T3p  = w_misc + 16;                       // C*A8 (<= 8192)
    float* w_partY  = w_T3p + 8192;                    // KSPLIT*NC
    float* w_partT1 = w_partY + KSPLIT * NC;           // KSPLIT*NC
    float* w_partT2 = w_partT1 + KSPLIT * NC;          // KSPLIT*NC
    unsigned short* w_featb = (unsigned short*)(w_partT2 + KSPLIT * NC);  // NA
    unsigned short* w_Wb    = w_featb + NA;            // CA
    unsigned short* w_W2b   = w_Wb + CA;               // CA
    unsigned short* w_Cb    = w_W2b + CA;              // CA
    unsigned short* w_Gb    = w_Cb + CA;               // CA

    prep_sort<<<NA / 2048, 256, 0, stream>>>(feat, w_featb, NA, labels,
                                             w_cnt, w_off, w_rows, w_misc, Nn, C);
    dim3 g2(A8, C);
    finalize_stats<<<g2, 256, 0, stream>>>(w_featb, w_cnt, w_off, w_rows,
                                           ave, cov, amount, W, feat,
                                           d_out, off_ave, off_cov, off_amt,
                                           w_Wb, w_W2b, w_Cb, w_Gb, w_T3p, A, A8);
    dim3 g3(Cpad / 64, Nn / 64, KSPLIT);
    triple_gemm_mfma<<<g3, 256, 0, stream>>>(w_featb, w_Wb, w_W2b, w_Cb, w_Gb,
                                             labels, w_partY, w_partT1, w_partT2,
                                             Cpad, A, NC);
    epilogue_rowloss<<<Nn, 256, 0, stream>>>(w_partY, w_partT1, w_partT2, w_T3p,
                                             bias, feat, labels, d_out, off_y,
                                             w_misc, C, Cpad, A8, ratiop, NC, Nn);
}